// Round 2
// baseline (726.194 us; speedup 1.0000x reference)
//
#include <hip/hip_runtime.h>
#include <math.h>

#define BATCH 64
#define TIME 400
#define BT (BATCH * TIME)   // 25600
#define S 25                // states
#define CH 80               // channels
#define CD (CH * CH)        // 6400

#define NTHREADS 256

// c_kernel geometry: 320 threads * 4 cols = 1280-col tile -> 5 exact tiles
#define C_THREADS 320
#define CPT 4
#define CD_TILE (C_THREADS * CPT)   // 1280
#define ROWS 64

typedef float v4f __attribute__((ext_vector_type(4)));

// scale[k] = softplus(alpha_scaling[k]), numerically stable
__global__ void scale_kernel(const float* __restrict__ alpha_scaling,
                             float* __restrict__ scale) {
    int k = threadIdx.x;
    if (k < S) {
        float x = alpha_scaling[k];
        scale[k] = fmaxf(x, 0.0f) + log1pf(expf(-fabsf(x)));
    }
}

// m_t[bt][c] = sum_k alpha[bt][k] * scale[k] * mu[k][c]
// one float4 of output per thread; mu (8 KB) staged in LDS
__global__ __launch_bounds__(NTHREADS) void m_kernel(
    const float* __restrict__ alpha, const float* __restrict__ mu,
    const float* __restrict__ scale, float* __restrict__ out_m) {
    __shared__ float s_mu[S * CH];
    __shared__ float s_scale[S];
    for (int i = threadIdx.x; i < S * CH; i += NTHREADS) s_mu[i] = mu[i];
    if (threadIdx.x < S) s_scale[threadIdx.x] = scale[threadIdx.x];
    __syncthreads();

    int i4 = blockIdx.x * NTHREADS + threadIdx.x;  // float4 index
    const int total4 = BT * CH / 4;
    if (i4 >= total4) return;
    int e = i4 * 4;
    int bt = e / CH;            // CH=80 divisible by 4 -> float4 never crosses a row
    int c = e - bt * CH;
    const float* arow = alpha + (size_t)bt * S;
    v4f acc = {0.f, 0.f, 0.f, 0.f};
#pragma unroll
    for (int k = 0; k < S; k++) {
        float a = arow[k] * s_scale[k];
        v4f m4 = *(const v4f*)&s_mu[k * CH + c];
        acc += a * m4;
    }
    __builtin_nontemporal_store(acc, (v4f*)&out_m[e]);
}

// C_t[bt][cd] = sum_k alpha[bt][k]*scale[k] * D[k][cd]
// No LDS. Each thread owns 4 adjacent output columns:
//   d[k] = scale[k]*D[k][c0..c0+3] held in VGPRs (~100), loaded once per block
//   from L2-resident D (640 KB). alpha is block-uniform -> SGPRs via s_load,
//   explicitly double-buffered one row ahead so the s_load latency overlaps
//   the previous row's FMAs. 4 independent FMA chains per row give 2x ILP
//   slack (200-cyc issue vs 100-cyc chain latency). Stores are nontemporal
//   dwordx4 (write stream is never re-read; keeps D/alpha L2-resident).
__global__ __launch_bounds__(C_THREADS) void c_kernel(
    const float* __restrict__ alpha, const float* __restrict__ D,
    const float* __restrict__ scale, float* __restrict__ out_c) {
    const int cd0 = blockIdx.x * CD_TILE;     // 5 exact tiles, no tail
    const int bt0 = blockIdx.y * ROWS;        // 400 row tiles
    const int c0 = cd0 + CPT * (int)threadIdx.x;

    // Load this thread's 4 D columns for all k, scale folded in.
    v4f d[S];
#pragma unroll
    for (int k = 0; k < S; ++k) {
        float sc = scale[k];  // uniform -> SGPR
        v4f dv = *(const v4f*)&D[(size_t)k * CD + c0];
        d[k] = dv * sc;
    }

    const float* arow = alpha + (size_t)bt0 * S;
    float* crow = out_c + (size_t)bt0 * CD + c0;

    // uniform -> SGPR double buffer
    float a_cur[S], a_nxt[S];
#pragma unroll
    for (int k = 0; k < S; ++k) a_cur[k] = arow[k];

    for (int r = 0; r < ROWS - 1; ++r) {
        const float* anext = arow + S;
#pragma unroll
        for (int k = 0; k < S; ++k) a_nxt[k] = anext[k];  // s_loads, overlap FMAs
        v4f acc = {0.f, 0.f, 0.f, 0.f};
#pragma unroll
        for (int k = 0; k < S; ++k) acc = a_cur[k] * d[k] + acc;
        __builtin_nontemporal_store(acc, (v4f*)crow);
#pragma unroll
        for (int k = 0; k < S; ++k) a_cur[k] = a_nxt[k];  // s_mov, SALU pipe
        arow += S;
        crow += CD;
    }
    // last row (no prefetch)
    {
        v4f acc = {0.f, 0.f, 0.f, 0.f};
#pragma unroll
        for (int k = 0; k < S; ++k) acc = a_cur[k] * d[k] + acc;
        __builtin_nontemporal_store(acc, (v4f*)crow);
    }
}

extern "C" void kernel_launch(void* const* d_in, const int* in_sizes, int n_in,
                              void* d_out, int out_size, void* d_ws, size_t ws_size,
                              hipStream_t stream) {
    const float* alpha = (const float*)d_in[0];          // [64,400,25]
    const float* mu = (const float*)d_in[1];             // [25,80]
    const float* D = (const float*)d_in[2];              // [25,80,80]
    const float* alpha_scaling = (const float*)d_in[3];  // [25]

    float* out = (float*)d_out;
    float* out_m = out;               // [25600,80]
    float* out_c = out + BT * CH;     // [25600,6400]
    float* scale = (float*)d_ws;      // 25 floats

    scale_kernel<<<1, 64, 0, stream>>>(alpha_scaling, scale);

    const int total4 = BT * CH / 4;  // 512000
    m_kernel<<<(total4 + NTHREADS - 1) / NTHREADS, NTHREADS, 0, stream>>>(
        alpha, mu, scale, out_m);

    dim3 grid(CD / CD_TILE, BT / ROWS);  // (5, 400)
    c_kernel<<<grid, C_THREADS, 0, stream>>>(alpha, D, scale, out_c);
}